// Round 1
// baseline (129.514 us; speedup 1.0000x reference)
//
#include <hip/hip_runtime.h>
#include <hip/hip_bf16.h>

// LinearPredictionHead: 4-expert last-token linear heads + dense-gate log-sum-exp combine.
// out[b,p,c] = log( sum_e gates[b,e] * exp( dot(xs_e[b,c,-1,:], W_e[:,p]) + b_e[p] ) )
// M=2048 (B*C), K=1024, N=720, E=4. bf16 MFMA 16x16x32, fused epilogue.

typedef __attribute__((ext_vector_type(4))) float f32x4;
typedef __attribute__((ext_vector_type(8))) short bf16x8;
typedef __attribute__((ext_vector_type(4))) unsigned short u16x4;

#define EPSV 2.2204460492503131e-16f

__device__ __forceinline__ unsigned short f2bf(float f) {
  unsigned u = __builtin_bit_cast(unsigned, f);
  u += 0x7fffu + ((u >> 16) & 1u);   // round-to-nearest-even
  return (unsigned short)(u >> 16);
}

__global__ __launch_bounds__(256) void moe_head_kernel(
    const float* __restrict__ xs0, const float* __restrict__ xs1,
    const float* __restrict__ xs2, const float* __restrict__ xs3,
    const float* __restrict__ gates,
    const float* __restrict__ W0, const float* __restrict__ b0,
    const float* __restrict__ W1, const float* __restrict__ b1,
    const float* __restrict__ W2, const float* __restrict__ b2,
    const float* __restrict__ W3, const float* __restrict__ b3,
    float* __restrict__ out)
{
  // LDS: A tile [64 rows][64 k] bf16 (swizzled), B tile [64 n][64 k] bf16 (swizzled),
  // plus per-wave 32x36 f32 transpose buffer for coalesced stores.
  __shared__ __align__(16) unsigned short a_lds[64 * 64];
  __shared__ __align__(16) unsigned short b_lds[64 * 64];
  __shared__ __align__(16) float t_lds[4][32 * 36];

  const int tid  = threadIdx.x;
  const int lane = tid & 63;
  const int wid  = tid >> 6;      // 4 waves
  const int wm   = wid >> 1;      // 0..1 : which 32-row half (== which b within tile)
  const int wn   = wid & 1;       // 0..1 : which 32-col half
  const int nt = blockIdx.x;      // 0..11  (N tiles of 64; last is ragged 720-704=16)
  const int mt = blockIdx.y;      // 0..31  (M tiles of 64)
  const int mbase = mt * 64;
  const int nbase = nt * 64;

  const float* xarr[4] = {xs0, xs1, xs2, xs3};
  const float* Warr[4] = {W0, W1, W2, W3};
  const float* barr[4] = {b0, b1, b2, b3};
  constexpr int Larr[4] = {32, 16, 8, 4};

  f32x4 comb[2][2] = {};   // combined sum_e g*exp(o) accumulator (per-lane fragment)

#pragma unroll
  for (int e = 0; e < 4; ++e) {
    const int L = Larr[e];
    const float* xlast = xarr[e] + (size_t)(L - 1) * 1024;  // last token of row 0
    const size_t xstride = (size_t)L * 1024;                // row (b,c) stride in floats
    const float* Wp = Warr[e];

    f32x4 acc[2][2] = {};

    for (int kt = 0; kt < 16; ++kt) {
      const int k0 = kt * 64;
      __syncthreads();   // previous compute done before overwriting LDS

      // ---- stage A: X[mbase..+64][k0..+64] f32 -> bf16, swizzled LDS ----
      {
        const int k_l = (tid & 15) * 4;   // 4-float chunk within the 64-k tile
        const int r0  = tid >> 4;         // 0..15
#pragma unroll
        for (int j = 0; j < 4; ++j) {
          const int row = r0 + j * 16;
          const float* src = xlast + (size_t)(mbase + row) * xstride + (k0 + k_l);
          f32x4 v = *(const f32x4*)src;
          u16x4 pk;
          pk[0] = f2bf(v[0]); pk[1] = f2bf(v[1]); pk[2] = f2bf(v[2]); pk[3] = f2bf(v[3]);
          const int byte = (row * 128 + k_l * 2) ^ ((row & 7) << 4);
          *(u16x4*)((char*)a_lds + byte) = pk;
        }
      }
      // ---- stage B: W[k0..+64][nbase..+64] f32 -> bf16, transposed [n][k], swizzled ----
      {
        const int n_l = tid & 63;
        const int kq  = tid >> 6;         // 0..3
        const int n_g = nbase + n_l;
        const bool nok = (n_g < 720);
        const float* wcol = Wp + n_g;     // column n_g, stride 720
#pragma unroll
        for (int g = 0; g < 4; ++g) {
          const int k_l = kq * 4 + g * 16;
          float w0 = 0.f, w1 = 0.f, w2 = 0.f, w3 = 0.f;
          if (nok) {
            const float* s = wcol + (size_t)(k0 + k_l) * 720;
            w0 = s[0]; w1 = s[720]; w2 = s[1440]; w3 = s[2160];
          }
          u16x4 pk;
          pk[0] = f2bf(w0); pk[1] = f2bf(w1); pk[2] = f2bf(w2); pk[3] = f2bf(w3);
          const int byte = (n_l * 128 + k_l * 2) ^ ((n_l & 7) << 4);
          *(u16x4*)((char*)b_lds + byte) = pk;
        }
      }
      __syncthreads();

      // ---- compute: 2 k-slices x 2x2 fragments of 16x16x32 ----
#pragma unroll
      for (int ks = 0; ks < 2; ++ks) {
        const int kb2 = (ks * 32 + (lane >> 4) * 8) * 2;  // k byte offset in a row
        bf16x8 af[2], bfr[2];
#pragma unroll
        for (int mf = 0; mf < 2; ++mf) {
          const int r = wm * 32 + mf * 16 + (lane & 15);
          const int byte = (r * 128 + kb2) ^ ((r & 7) << 4);
          af[mf] = *(const bf16x8*)((const char*)a_lds + byte);
        }
#pragma unroll
        for (int nf = 0; nf < 2; ++nf) {
          const int r = wn * 32 + nf * 16 + (lane & 15);
          const int byte = (r * 128 + kb2) ^ ((r & 7) << 4);
          bfr[nf] = *(const bf16x8*)((const char*)b_lds + byte);
        }
#pragma unroll
        for (int mf = 0; mf < 2; ++mf)
#pragma unroll
          for (int nf = 0; nf < 2; ++nf)
            acc[mf][nf] = __builtin_amdgcn_mfma_f32_16x16x32_bf16(
                af[mf], bfr[nf], acc[mf][nf], 0, 0, 0);
      }
    } // kt

    // ---- expert epilogue: comb += g * exp(acc + bias) ----
    {
      const int b_idx = mt * 2 + wm;               // wave's rows are a single b
      const float g = gates[b_idx * 4 + e];
#pragma unroll
      for (int nf = 0; nf < 2; ++nf) {
        const int col = nbase + wn * 32 + nf * 16 + (lane & 15);
        const float bias = (col < 720) ? barr[e][col] : 0.0f;
#pragma unroll
        for (int mf = 0; mf < 2; ++mf)
#pragma unroll
          for (int j = 0; j < 4; ++j)
            comb[mf][nf][j] += g * __expf(acc[mf][nf][j] + bias);
      }
    }
  } // experts

  // ---- final: log, transpose 32x32 per wave in LDS, coalesced float4 stores ----
  {
    float* tl = &t_lds[wid][0];
#pragma unroll
    for (int mf = 0; mf < 2; ++mf)
#pragma unroll
      for (int nf = 0; nf < 2; ++nf)
#pragma unroll
        for (int j = 0; j < 4; ++j) {
          const int row_l = mf * 16 + (lane >> 4) * 4 + j;  // c index 0..31
          const int col_l = nf * 16 + (lane & 15);          // p-local 0..31
          float v = comb[mf][nf][j];
          v = (v == 0.0f) ? EPSV : v;
          tl[col_l * 36 + row_l] = __logf(v);
        }
    __syncthreads();
    const int b_idx = mt * 2 + wm;
    const int pbase = nbase + wn * 32;
#pragma unroll
    for (int it = 0; it < 4; ++it) {
      const int p_l = it * 8 + (lane >> 3);
      const int p = pbase + p_l;
      if (p < 720) {
        f32x4 v = *(const f32x4*)(tl + p_l * 36 + (lane & 7) * 4);
        *(f32x4*)(out + ((size_t)b_idx * 720 + p) * 32 + (lane & 7) * 4) = v;
      }
    }
  }
}

extern "C" void kernel_launch(void* const* d_in, const int* in_sizes, int n_in,
                              void* d_out, int out_size, void* d_ws, size_t ws_size,
                              hipStream_t stream) {
  dim3 grid(12, 32);   // 12 N-tiles x 32 M-tiles = 384 blocks
  dim3 block(256);
  moe_head_kernel<<<grid, block, 0, stream>>>(
      (const float*)d_in[0], (const float*)d_in[1],
      (const float*)d_in[2], (const float*)d_in[3],
      (const float*)d_in[4],
      (const float*)d_in[5], (const float*)d_in[6],
      (const float*)d_in[7], (const float*)d_in[8],
      (const float*)d_in[9], (const float*)d_in[10],
      (const float*)d_in[11], (const float*)d_in[12],
      (float*)d_out);
}

// Round 3
// 51.202 us; speedup vs baseline: 2.5295x; 2.5295x over previous
//
#include <hip/hip_runtime.h>
#include <hip/hip_bf16.h>

// LinearPredictionHead: 4-expert last-token linear heads + dense-gate log-sum-exp combine.
// out[b,p,c] = log( sum_e gates[b,e] * exp( dot(xs_e[b,c,-1,:], W_e[:,p]) + b_e[p] ) )
// Round 3: same as round 2 (prep to bf16 in ws + global_load_lds GEMM) but the
// K-loop uses the PROVEN single-__syncthreads 2-phase structure (m97/T3-minimal)
// instead of counted vmcnt + raw s_barrier, which raced under graph replay.

typedef __attribute__((ext_vector_type(4))) float f32x4;
typedef __attribute__((ext_vector_type(8))) short bf16x8;
typedef __attribute__((ext_vector_type(4))) unsigned short u16x4;
typedef __attribute__((ext_vector_type(8))) unsigned short u16x8;

#define EPSV 2.2204460492503131e-16f

__device__ __forceinline__ unsigned short f2bf(float f) {
  unsigned u = __builtin_bit_cast(unsigned, f);
  u += 0x7fffu + ((u >> 16) & 1u);   // round-to-nearest-even
  return (unsigned short)(u >> 16);
}

__device__ __forceinline__ void gload_lds16(const void* g, void* l) {
  __builtin_amdgcn_global_load_lds(
      (const __attribute__((address_space(1))) unsigned int*)g,
      (__attribute__((address_space(3))) unsigned int*)l, 16, 0, 0);
}

// ---------------- prep 1: X last tokens -> bf16 [4][2048][1024] ----------------
__global__ __launch_bounds__(256) void prep_x(
    const float* __restrict__ xs0, const float* __restrict__ xs1,
    const float* __restrict__ xs2, const float* __restrict__ xs3,
    unsigned short* __restrict__ Xb)
{
  const int i = blockIdx.x * 256 + threadIdx.x;  // 0..1048575 (8 elems each)
  const int e = i >> 18;                         // 262144 chunks per expert
  const int rem = i & 262143;
  const int m = rem >> 7;
  const int kc = rem & 127;
  const float* xp = (e == 0) ? xs0 : (e == 1) ? xs1 : (e == 2) ? xs2 : xs3;
  const int L = 32 >> e;                         // 32,16,8,4
  const float* src = xp + ((size_t)m * L + (L - 1)) * 1024 + kc * 8;
  f32x4 v0 = *(const f32x4*)src;
  f32x4 v1 = *(const f32x4*)(src + 4);
  u16x8 pk;
  pk[0] = f2bf(v0[0]); pk[1] = f2bf(v0[1]); pk[2] = f2bf(v0[2]); pk[3] = f2bf(v0[3]);
  pk[4] = f2bf(v1[0]); pk[5] = f2bf(v1[1]); pk[6] = f2bf(v1[2]); pk[7] = f2bf(v1[3]);
  *(u16x8*)(Xb + ((size_t)e * 2048 + m) * 1024 + kc * 8) = pk;
}

// ---------------- prep 2: W [1024][720] -> bf16 W^T [4][720][1024] ----------------
__global__ __launch_bounds__(256) void prep_w(
    const float* __restrict__ W0, const float* __restrict__ W1,
    const float* __restrict__ W2, const float* __restrict__ W3,
    unsigned short* __restrict__ Wb)
{
  __shared__ __align__(16) unsigned short tile[64 * 72];  // [n][k], stride 72
  const int e = blockIdx.z;
  const float* Wp = (e == 0) ? W0 : (e == 1) ? W1 : (e == 2) ? W2 : W3;
  const int k0 = blockIdx.x * 64;
  const int nb = blockIdx.y * 64;
  const int tid = threadIdx.x;
  const int n_c = tid & 15;     // f32x4 chunk in n
  const int r = tid >> 4;       // k rows
  const int n0 = nb + n_c * 4;
#pragma unroll
  for (int j = 0; j < 4; ++j) {
    const int row = r + j * 16;
    f32x4 v = {0.f, 0.f, 0.f, 0.f};
    if (n0 < 720) v = *(const f32x4*)(Wp + (size_t)(k0 + row) * 720 + n0);
#pragma unroll
    for (int d = 0; d < 4; ++d) tile[(n_c * 4 + d) * 72 + row] = f2bf(v[d]);
  }
  __syncthreads();
  const int n_l = tid >> 2;
  const int kq = tid & 3;
  if (nb + n_l < 720) {
#pragma unroll
    for (int q = 0; q < 2; ++q) {
      const int chunk = q * 4 + kq;
      *(u16x8*)(Wb + ((size_t)e * 720 + nb + n_l) * 1024 + k0 + chunk * 8) =
          *(const u16x8*)(tile + n_l * 72 + chunk * 8);
    }
  }
}

// ---------------- main: bf16 GEMM + fused exp/gate/log epilogue ----------------
// BM=32 (one batch b per block), BN=64, BK=64, 2 waves (each 32x32), dbuf LDS.
// Single __syncthreads() per K-step: stage(next) -> compute(cur) -> sync -> swap.
__global__ __launch_bounds__(128) void moe_gemm(
    const unsigned short* __restrict__ Xb, const unsigned short* __restrict__ Wb,
    const float* __restrict__ gates,
    const float* __restrict__ b0, const float* __restrict__ b1,
    const float* __restrict__ b2, const float* __restrict__ b3,
    float* __restrict__ out)
{
  __shared__ __align__(16) unsigned char smem[24576];
  unsigned short* a_lds = (unsigned short*)smem;           // [2][32*64] bf16 = 8KB
  unsigned short* b_lds = (unsigned short*)(smem + 8192);  // [2][64*64] bf16 = 16KB

  const int tid = threadIdx.x;
  const int lane = tid & 63;
  const int w = tid >> 6;            // 0..1, n-half
  const int nt = blockIdx.x;         // 12 N-tiles of 64
  const int bI = blockIdx.y;         // 64 M-tiles of 32 == batch index b
  const int nbase = nt * 64;
  const size_t abase = (size_t)bI * 32 * 1024;   // within expert's [2048][1024]

  // preload gates and biases (loop-invariant)
  const float* barr[4] = {b0, b1, b2, b3};
  float gate_r[4], bias_r[4][2];
#pragma unroll
  for (int e = 0; e < 4; ++e) {
    gate_r[e] = gates[bI * 4 + e];
#pragma unroll
    for (int nf = 0; nf < 2; ++nf) {
      int col = nbase + w * 32 + nf * 16 + (lane & 15);
      bias_r[e][nf] = barr[e][col < 720 ? col : 719];
    }
  }

  // stage one (e, k0) tile pair into buffer buf: 6 global_load_lds per thread.
  // LDS layout is linear [row][64k] (lane-linear dst as global_load_lds needs);
  // read side XORs ((row&7)<<4), so the global source is pre-swizzled with the
  // same involution (rule m173/#21).
  auto stage = [&](int e2, int k0, int buf) {
    {
      const unsigned short* src = Xb + (size_t)e2 * 2048 * 1024 + abase + k0;
      unsigned short* dst = a_lds + buf * 2048;
#pragma unroll
      for (int j = 0; j < 2; ++j) {
        const int C = j * 128 + tid;        // 16B chunk 0..255
        const int row = C >> 3, c = C & 7;
        gload_lds16(src + row * 1024 + ((c ^ (row & 7)) * 8), dst + C * 8);
      }
    }
    {
      const unsigned short* src = Wb + (size_t)e2 * 720 * 1024 + k0;
      unsigned short* dst = b_lds + buf * 4096;
#pragma unroll
      for (int j = 0; j < 4; ++j) {
        const int C = j * 128 + tid;        // 16B chunk 0..511
        const int row = C >> 3, c = C & 7;
        int n = nbase + row; if (n > 719) n = 719;   // clamp: finite garbage, stores guarded
        gload_lds16(src + (size_t)n * 1024 + ((c ^ (row & 7)) * 8), dst + C * 8);
      }
    }
  };

  auto compute = [&](int buf, f32x4 (&acc)[2][2]) {
    const unsigned short* al = a_lds + buf * 2048;
    const unsigned short* bl = b_lds + buf * 4096;
#pragma unroll
    for (int ks = 0; ks < 2; ++ks) {
      const int kb = ks * 64 + (lane >> 4) * 16;   // byte offset in 128B row
      bf16x8 af[2], bfm[2];
#pragma unroll
      for (int mf = 0; mf < 2; ++mf) {
        const int r = mf * 16 + (lane & 15);
        const int byte = (r * 128 + kb) ^ ((r & 7) << 4);
        af[mf] = *(const bf16x8*)((const char*)al + byte);
      }
#pragma unroll
      for (int nf = 0; nf < 2; ++nf) {
        const int r = w * 32 + nf * 16 + (lane & 15);
        const int byte = (r * 128 + kb) ^ ((r & 7) << 4);
        bfm[nf] = *(const bf16x8*)((const char*)bl + byte);
      }
#pragma unroll
      for (int mf = 0; mf < 2; ++mf)
#pragma unroll
        for (int nf = 0; nf < 2; ++nf)
          acc[mf][nf] = __builtin_amdgcn_mfma_f32_16x16x32_bf16(
              af[mf], bfm[nf], acc[mf][nf], 0, 0, 0);
    }
  };

  f32x4 comb[2][2] = {};
  int cur = 0;
  stage(0, 0, 0);        // prologue fill
  __syncthreads();       // drain: buf0 ready

#pragma unroll
  for (int e = 0; e < 4; ++e) {
    f32x4 acc[2][2] = {};
    for (int kt = 0; kt < 16; ++kt) {
      const bool has_next = !(e == 3 && kt == 15);
      if (has_next) {
        const int e2 = (kt == 15) ? e + 1 : e;
        const int k2 = (kt == 15) ? 0 : (kt + 1) * 64;
        stage(e2, k2, cur ^ 1);     // issue next-tile loads; they fly during compute
      }
      compute(cur, acc);            // ds_read + 8 MFMA on current buffer
      __syncthreads();              // implicit vmcnt(0)+lgkmcnt(0) drain + barrier:
                                    // next buffer ready, all reads of cur done
      cur ^= 1;
    }
    // expert epilogue: comb += g * exp(acc + bias)
    const float g = gate_r[e];
#pragma unroll
    for (int nf = 0; nf < 2; ++nf)
#pragma unroll
      for (int mf = 0; mf < 2; ++mf)
#pragma unroll
        for (int j = 0; j < 4; ++j)
          comb[mf][nf][j] += g * __expf(acc[mf][nf][j] + bias_r[e][nf]);
  }

  // final: log + per-wave 32x32 transpose in LDS (stride 36 f32), coalesced stores
  float* tl = (float*)smem + w * (32 * 36);
#pragma unroll
  for (int mf = 0; mf < 2; ++mf)
#pragma unroll
    for (int nf = 0; nf < 2; ++nf)
#pragma unroll
      for (int j = 0; j < 4; ++j) {
        const int row_l = mf * 16 + (lane >> 4) * 4 + j;  // c 0..31
        const int col_l = nf * 16 + (lane & 15);          // p-local 0..31
        float v = comb[mf][nf][j];
        v = (v == 0.0f) ? EPSV : v;
        tl[col_l * 36 + row_l] = __logf(v);
      }
  __syncthreads();
  const int pbase = nbase + w * 32;
#pragma unroll
  for (int it = 0; it < 4; ++it) {
    const int p_l = it * 8 + (lane >> 3);
    const int p = pbase + p_l;
    if (p < 720) {
      f32x4 v = *(const f32x4*)(tl + p_l * 36 + (lane & 7) * 4);
      *(f32x4*)(out + ((size_t)bI * 720 + p) * 32 + (lane & 7) * 4) = v;
    }
  }
}

// ---------------- round-1 fallback (used only if ws is too small) ----------------
__global__ __launch_bounds__(256) void moe_head_fallback(
    const float* __restrict__ xs0, const float* __restrict__ xs1,
    const float* __restrict__ xs2, const float* __restrict__ xs3,
    const float* __restrict__ gates,
    const float* __restrict__ W0, const float* __restrict__ b0,
    const float* __restrict__ W1, const float* __restrict__ b1,
    const float* __restrict__ W2, const float* __restrict__ b2,
    const float* __restrict__ W3, const float* __restrict__ b3,
    float* __restrict__ out)
{
  __shared__ __align__(16) unsigned short a_lds[64 * 64];
  __shared__ __align__(16) unsigned short b_lds[64 * 64];
  __shared__ __align__(16) float t_lds[4][32 * 36];
  const int tid = threadIdx.x;
  const int lane = tid & 63;
  const int wid = tid >> 6;
  const int wm = wid >> 1, wn = wid & 1;
  const int nt = blockIdx.x, mt = blockIdx.y;
  const int mbase = mt * 64, nbase = nt * 64;
  const float* xarr[4] = {xs0, xs1, xs2, xs3};
  const float* Warr[4] = {W0, W1, W2, W3};
  const float* barr[4] = {b0, b1, b2, b3};
  constexpr int Larr[4] = {32, 16, 8, 4};
  f32x4 comb[2][2] = {};
#pragma unroll
  for (int e = 0; e < 4; ++e) {
    const int L = Larr[e];
    const float* xlast = xarr[e] + (size_t)(L - 1) * 1024;
    const size_t xstride = (size_t)L * 1024;
    const float* Wp = Warr[e];
    f32x4 acc[2][2] = {};
    for (int kt = 0; kt < 16; ++kt) {
      const int k0 = kt * 64;
      __syncthreads();
      {
        const int k_l = (tid & 15) * 4;
        const int r0 = tid >> 4;
#pragma unroll
        for (int j = 0; j < 4; ++j) {
          const int row = r0 + j * 16;
          f32x4 v = *(const f32x4*)(xlast + (size_t)(mbase + row) * xstride + (k0 + k_l));
          u16x4 pk;
          pk[0] = f2bf(v[0]); pk[1] = f2bf(v[1]); pk[2] = f2bf(v[2]); pk[3] = f2bf(v[3]);
          const int byte = (row * 128 + k_l * 2) ^ ((row & 7) << 4);
          *(u16x4*)((char*)a_lds + byte) = pk;
        }
      }
      {
        const int n_l = tid & 63;
        const int kq = tid >> 6;
        const int n_g = nbase + n_l;
        const bool nok = (n_g < 720);
        const float* wcol = Wp + n_g;
#pragma unroll
        for (int g = 0; g < 4; ++g) {
          const int k_l = kq * 4 + g * 16;
          float w0 = 0.f, w1 = 0.f, w2 = 0.f, w3 = 0.f;
          if (nok) {
            const float* s = wcol + (size_t)(k0 + k_l) * 720;
            w0 = s[0]; w1 = s[720]; w2 = s[1440]; w3 = s[2160];
          }
          u16x4 pk;
          pk[0] = f2bf(w0); pk[1] = f2bf(w1); pk[2] = f2bf(w2); pk[3] = f2bf(w3);
          const int byte = (n_l * 128 + k_l * 2) ^ ((n_l & 7) << 4);
          *(u16x4*)((char*)b_lds + byte) = pk;
        }
      }
      __syncthreads();
#pragma unroll
      for (int ks = 0; ks < 2; ++ks) {
        const int kb2 = (ks * 32 + (lane >> 4) * 8) * 2;
        bf16x8 af[2], bfr[2];
#pragma unroll
        for (int mf = 0; mf < 2; ++mf) {
          const int r = wm * 32 + mf * 16 + (lane & 15);
          const int byte = (r * 128 + kb2) ^ ((r & 7) << 4);
          af[mf] = *(const bf16x8*)((const char*)a_lds + byte);
        }
#pragma unroll
        for (int nf = 0; nf < 2; ++nf) {
          const int r = wn * 32 + nf * 16 + (lane & 15);
          const int byte = (r * 128 + kb2) ^ ((r & 7) << 4);
          bfr[nf] = *(const bf16x8*)((const char*)b_lds + byte);
        }
#pragma unroll
        for (int mf = 0; mf < 2; ++mf)
#pragma unroll
          for (int nf = 0; nf < 2; ++nf)
            acc[mf][nf] = __builtin_amdgcn_mfma_f32_16x16x32_bf16(
                af[mf], bfr[nf], acc[mf][nf], 0, 0, 0);
      }
    }
    {
      const int b_idx = mt * 2 + wm;
      const float g = gates[b_idx * 4 + e];
#pragma unroll
      for (int nf = 0; nf < 2; ++nf) {
        const int col = nbase + wn * 32 + nf * 16 + (lane & 15);
        const float bias = (col < 720) ? barr[e][col] : 0.0f;
#pragma unroll
        for (int mf = 0; mf < 2; ++mf)
#pragma unroll
          for (int j = 0; j < 4; ++j)
            comb[mf][nf][j] += g * __expf(acc[mf][nf][j] + bias);
      }
    }
  }
  {
    float* tl = &t_lds[wid][0];
#pragma unroll
    for (int mf = 0; mf < 2; ++mf)
#pragma unroll
      for (int nf = 0; nf < 2; ++nf)
#pragma unroll
        for (int j = 0; j < 4; ++j) {
          const int row_l = mf * 16 + (lane >> 4) * 4 + j;
          const int col_l = nf * 16 + (lane & 15);
          float v = comb[mf][nf][j];
          v = (v == 0.0f) ? EPSV : v;
          tl[col_l * 36 + row_l] = __logf(v);
        }
    __syncthreads();
    const int b_idx = mt * 2 + wm;
    const int pbase = nbase + wn * 32;
#pragma unroll
    for (int it = 0; it < 4; ++it) {
      const int p_l = it * 8 + (lane >> 3);
      const int p = pbase + p_l;
      if (p < 720) {
        f32x4 v = *(const f32x4*)(tl + p_l * 36 + (lane & 7) * 4);
        *(f32x4*)(out + ((size_t)b_idx * 720 + p) * 32 + (lane & 7) * 4) = v;
      }
    }
  }
}

extern "C" void kernel_launch(void* const* d_in, const int* in_sizes, int n_in,
                              void* d_out, int out_size, void* d_ws, size_t ws_size,
                              hipStream_t stream) {
  const size_t xb_elems = (size_t)4 * 2048 * 1024;
  const size_t wb_elems = (size_t)4 * 720 * 1024;
  const size_t need = (xb_elems + wb_elems) * 2;
  if (ws_size >= need) {
    unsigned short* Xb = (unsigned short*)d_ws;
    unsigned short* Wb = Xb + xb_elems;
    prep_x<<<4096, 256, 0, stream>>>(
        (const float*)d_in[0], (const float*)d_in[1],
        (const float*)d_in[2], (const float*)d_in[3], Xb);
    prep_w<<<dim3(16, 12, 4), 256, 0, stream>>>(
        (const float*)d_in[5], (const float*)d_in[7],
        (const float*)d_in[9], (const float*)d_in[11], Wb);
    moe_gemm<<<dim3(12, 64), 128, 0, stream>>>(
        Xb, Wb, (const float*)d_in[4],
        (const float*)d_in[6], (const float*)d_in[8],
        (const float*)d_in[10], (const float*)d_in[12],
        (float*)d_out);
  } else {
    moe_head_fallback<<<dim3(12, 32), 256, 0, stream>>>(
        (const float*)d_in[0], (const float*)d_in[1],
        (const float*)d_in[2], (const float*)d_in[3],
        (const float*)d_in[4],
        (const float*)d_in[5], (const float*)d_in[6],
        (const float*)d_in[7], (const float*)d_in[8],
        (const float*)d_in[9], (const float*)d_in[10],
        (const float*)d_in[11], (const float*)d_in[12],
        (float*)d_out);
  }
}

// Round 4
// 45.267 us; speedup vs baseline: 2.8611x; 1.1311x over previous
//
#include <hip/hip_runtime.h>
#include <hip/hip_bf16.h>

// LinearPredictionHead: 4-expert last-token linear heads + dense-gate log-sum-exp combine.
// out[b,p,c] = log( sum_e gates[b,e] * exp( dot(xs_e[b,c,-1,:], W_e[:,p]) + b_e[p] ) )
// Round 4: expert-split GEMM blocks (combine is additive across experts) writing
// g*exp(o_e) into per-expert f32 planes; reduce kernel sums+logs+transposes.
// 64x64 tiles / 4 waves, bijective XCD swizzle, fused prep dispatch.

typedef __attribute__((ext_vector_type(4))) float f32x4;
typedef __attribute__((ext_vector_type(8))) short bf16x8;
typedef __attribute__((ext_vector_type(4))) unsigned short u16x4;
typedef __attribute__((ext_vector_type(8))) unsigned short u16x8;

#define EPSV 2.2204460492503131e-16f

__device__ __forceinline__ unsigned short f2bf(float f) {
  unsigned u = __builtin_bit_cast(unsigned, f);
  u += 0x7fffu + ((u >> 16) & 1u);   // round-to-nearest-even
  return (unsigned short)(u >> 16);
}

__device__ __forceinline__ void gload_lds16(const void* g, void* l) {
  __builtin_amdgcn_global_load_lds(
      (const __attribute__((address_space(1))) unsigned int*)g,
      (__attribute__((address_space(3))) unsigned int*)l, 16, 0, 0);
}

// ---------------- prep (fused): X last tokens -> bf16 [4][2048][1024]
//                               + W [1024][720] -> bf16 W^T [4][720][1024] ----
__global__ __launch_bounds__(256) void prep_fused(
    const float* __restrict__ xs0, const float* __restrict__ xs1,
    const float* __restrict__ xs2, const float* __restrict__ xs3,
    const float* __restrict__ W0, const float* __restrict__ W1,
    const float* __restrict__ W2, const float* __restrict__ W3,
    unsigned short* __restrict__ Xb, unsigned short* __restrict__ Wb)
{
  __shared__ __align__(16) unsigned short tile[64 * 72];  // W path only
  const int tid = threadIdx.x;
  if (blockIdx.x < 4096) {
    // ---- X path (validated round-2/3 prep_x) ----
    const int i = blockIdx.x * 256 + tid;          // 8 elems each
    const int e = i >> 18;
    const int rem = i & 262143;
    const int m = rem >> 7;
    const int kc = rem & 127;
    const float* xp = (e == 0) ? xs0 : (e == 1) ? xs1 : (e == 2) ? xs2 : xs3;
    const int L = 32 >> e;                         // 32,16,8,4
    const float* src = xp + ((size_t)m * L + (L - 1)) * 1024 + kc * 8;
    f32x4 v0 = *(const f32x4*)src;
    f32x4 v1 = *(const f32x4*)(src + 4);
    u16x8 pk;
    pk[0] = f2bf(v0[0]); pk[1] = f2bf(v0[1]); pk[2] = f2bf(v0[2]); pk[3] = f2bf(v0[3]);
    pk[4] = f2bf(v1[0]); pk[5] = f2bf(v1[1]); pk[6] = f2bf(v1[2]); pk[7] = f2bf(v1[3]);
    *(u16x8*)(Xb + ((size_t)e * 2048 + m) * 1024 + kc * 8) = pk;
  } else {
    // ---- W path (validated round-2/3 prep_w) ----
    const int wI = blockIdx.x - 4096;              // 0..767 = 16 k x 12 n x 4 e
    const int k0 = (wI & 15) * 64;
    const int rest = wI >> 4;
    const int nb = (rest % 12) * 64;
    const int e = rest / 12;
    const float* Wp = (e == 0) ? W0 : (e == 1) ? W1 : (e == 2) ? W2 : W3;
    const int n_c = tid & 15;
    const int r = tid >> 4;
    const int n0 = nb + n_c * 4;
#pragma unroll
    for (int j = 0; j < 4; ++j) {
      const int row = r + j * 16;
      f32x4 v = {0.f, 0.f, 0.f, 0.f};
      if (n0 < 720) v = *(const f32x4*)(Wp + (size_t)(k0 + row) * 720 + n0);
#pragma unroll
      for (int d = 0; d < 4; ++d) tile[(n_c * 4 + d) * 72 + row] = f2bf(v[d]);
    }
    __syncthreads();
    const int n_l = tid >> 2;
    const int kq = tid & 3;
    if (nb + n_l < 720) {
#pragma unroll
      for (int q = 0; q < 2; ++q) {
        const int chunk = q * 4 + kq;
        *(u16x8*)(Wb + ((size_t)e * 720 + nb + n_l) * 1024 + k0 + chunk * 8) =
            *(const u16x8*)(tile + n_l * 72 + chunk * 8);
      }
    }
  }
}

// ---------------- GEMM per expert: planes[e][m][p] = g * exp(o_e + bias) ------
// 64x64 tile, 4 waves (2 wm x 2 wn), BK=64, 16 K-steps, dbuf LDS,
// single-__syncthreads 2-phase (validated structure). Grid 1536 = 12nt*32mt*4e,
// bijective XCD-chunked swizzle (1536 % 8 == 0).
__global__ __launch_bounds__(256) void moe_gemm_e(
    const unsigned short* __restrict__ Xb, const unsigned short* __restrict__ Wb,
    const float* __restrict__ gates,
    const float* __restrict__ b0, const float* __restrict__ b1,
    const float* __restrict__ b2, const float* __restrict__ b3,
    float* __restrict__ planes)
{
  __shared__ __align__(16) unsigned char smem[32768];
  unsigned short* a_lds = (unsigned short*)smem;            // [2][64*64] = 16KB
  unsigned short* b_lds = (unsigned short*)(smem + 16384);  // [2][64*64] = 16KB

  const int tid = threadIdx.x;
  const int lane = tid & 63;
  const int wid = tid >> 6;
  const int wm = wid >> 1, wn = wid & 1;

  // XCD-chunked bijection: XCD x gets contiguous ids [x*192, (x+1)*192)
  const int id = ((int)blockIdx.x & 7) * 192 + ((int)blockIdx.x >> 3);
  const int nt = id % 12;
  const int mt = (id / 12) % 32;
  const int e  = id / 384;
  const int nbase = nt * 64;

  const float* barr[4] = {b0, b1, b2, b3};
  const int bI = mt * 2 + wm;                   // wave's 32 rows = one batch b
  const float g = gates[bI * 4 + e];
  float bias_r[2];
#pragma unroll
  for (int nf = 0; nf < 2; ++nf) {
    int col = nbase + wn * 32 + nf * 16 + (lane & 15);
    bias_r[nf] = barr[e][col < 720 ? col : 719];
  }

  const unsigned short* asrc = Xb + (size_t)e * 2048 * 1024 + (size_t)mt * 64 * 1024;
  const unsigned short* bsrc = Wb + (size_t)e * 720 * 1024;

  // stage: A tile 64x64 (512 chunks) + B tile 64x64 (512 chunks), 4 loads/thread.
  // LDS dst linear; global src pre-swizzled with the read-side XOR (m173/#21).
  auto stage = [&](int k0, int buf) {
#pragma unroll
    for (int j = 0; j < 2; ++j) {
      const int C = j * 256 + tid;
      const int row = C >> 3, c = C & 7;
      gload_lds16(asrc + (size_t)row * 1024 + k0 + ((c ^ (row & 7)) * 8),
                  a_lds + buf * 4096 + C * 8);
    }
#pragma unroll
    for (int j = 0; j < 2; ++j) {
      const int C = j * 256 + tid;
      const int row = C >> 3, c = C & 7;
      int n = nbase + row; if (n > 719) n = 719;  // clamp; stores guarded later
      gload_lds16(bsrc + (size_t)n * 1024 + k0 + ((c ^ (row & 7)) * 8),
                  b_lds + buf * 4096 + C * 8);
    }
  };

  auto compute = [&](int buf, f32x4 (&acc)[2][2]) {
    const unsigned short* al = a_lds + buf * 4096;
    const unsigned short* bl = b_lds + buf * 4096;
#pragma unroll
    for (int ks = 0; ks < 2; ++ks) {
      const int kb = ks * 64 + (lane >> 4) * 16;  // byte offset within 128B row
      bf16x8 af[2], bfm[2];
#pragma unroll
      for (int mf = 0; mf < 2; ++mf) {
        const int r = wm * 32 + mf * 16 + (lane & 15);
        const int byte = (r * 128 + kb) ^ ((r & 7) << 4);
        af[mf] = *(const bf16x8*)((const char*)al + byte);
      }
#pragma unroll
      for (int nf = 0; nf < 2; ++nf) {
        const int r = wn * 32 + nf * 16 + (lane & 15);
        const int byte = (r * 128 + kb) ^ ((r & 7) << 4);
        bfm[nf] = *(const bf16x8*)((const char*)bl + byte);
      }
#pragma unroll
      for (int mf = 0; mf < 2; ++mf)
#pragma unroll
        for (int nf = 0; nf < 2; ++nf)
          acc[mf][nf] = __builtin_amdgcn_mfma_f32_16x16x32_bf16(
              af[mf], bfm[nf], acc[mf][nf], 0, 0, 0);
    }
  };

  f32x4 acc[2][2] = {};
  int cur = 0;
  stage(0, 0);
  __syncthreads();
  for (int kt = 0; kt < 16; ++kt) {
    if (kt < 15) stage((kt + 1) * 64, cur ^ 1);  // next-tile loads fly during compute
    compute(cur, acc);
    __syncthreads();                             // drain + barrier (proven structure)
    cur ^= 1;
  }

  // epilogue: plane[e][m][p] = g * exp(acc + bias); 16-lane-consecutive-p stores
#pragma unroll
  for (int nf = 0; nf < 2; ++nf) {
    const int p = nbase + wn * 32 + nf * 16 + (lane & 15);
    if (p < 720) {
#pragma unroll
      for (int mf = 0; mf < 2; ++mf) {
        const int m0 = mt * 64 + wm * 32 + mf * 16 + ((lane >> 4) << 2);
        float* dst = planes + ((size_t)e * 2048 + m0) * 720 + p;
#pragma unroll
        for (int j = 0; j < 4; ++j)
          dst[j * 720] = g * __expf(acc[mf][nf][j] + bias_r[nf]);
      }
    }
  }
}

// ---------------- reduce: sum 4 planes, log, transpose -> out[b][p][c] --------
__global__ __launch_bounds__(128) void reduce_log(
    const float* __restrict__ planes, float* __restrict__ out)
{
  __shared__ __align__(16) float t[64 * 36];
  const int nt = blockIdx.x;         // 12 p-tiles of 64
  const int b  = blockIdx.y;         // 64 batches (32 c-rows each)
  const int nbase = nt * 64;
  const int tid = threadIdx.x;

#pragma unroll
  for (int it = 0; it < 4; ++it) {
    const int i = it * 128 + tid;    // 512 f32x4 tiles: 32 rows x 16 p-chunks
    const int row = i >> 4;          // c 0..31
    const int pc = i & 15;
    int p0 = nbase + pc * 4;
    if (p0 > 716) p0 = 716;          // clamp (values discarded by store guard)
    const size_t base = ((size_t)b * 32 + row) * 720 + p0;
    f32x4 s = *(const f32x4*)(planes + base);
    s += *(const f32x4*)(planes + (size_t)2048 * 720 + base);
    s += *(const f32x4*)(planes + (size_t)2 * 2048 * 720 + base);
    s += *(const f32x4*)(planes + (size_t)3 * 2048 * 720 + base);
#pragma unroll
    for (int d = 0; d < 4; ++d) {
      float v = s[d];
      v = (v == 0.0f) ? EPSV : v;
      t[(pc * 4 + d) * 36 + row] = __logf(v);
    }
  }
  __syncthreads();
#pragma unroll
  for (int it = 0; it < 4; ++it) {
    const int i = it * 128 + tid;    // 512 f32x4: 64 p x 8 c-chunks
    const int p_l = i >> 3;
    const int cc = i & 7;
    const int p = nbase + p_l;
    if (p < 720) {
      f32x4 v = *(const f32x4*)(t + p_l * 36 + cc * 4);
      *(f32x4*)(out + ((size_t)b * 720 + p) * 32 + cc * 4) = v;
    }
  }
}

// ---------------- round-1 fallback (used only if ws is too small) ----------------
__global__ __launch_bounds__(256) void moe_head_fallback(
    const float* __restrict__ xs0, const float* __restrict__ xs1,
    const float* __restrict__ xs2, const float* __restrict__ xs3,
    const float* __restrict__ gates,
    const float* __restrict__ W0, const float* __restrict__ b0,
    const float* __restrict__ W1, const float* __restrict__ b1,
    const float* __restrict__ W2, const float* __restrict__ b2,
    const float* __restrict__ W3, const float* __restrict__ b3,
    float* __restrict__ out)
{
  __shared__ __align__(16) unsigned short a_lds[64 * 64];
  __shared__ __align__(16) unsigned short b_lds[64 * 64];
  __shared__ __align__(16) float t_lds[4][32 * 36];
  const int tid = threadIdx.x;
  const int lane = tid & 63;
  const int wid = tid >> 6;
  const int wm = wid >> 1, wn = wid & 1;
  const int nt = blockIdx.x, mt = blockIdx.y;
  const int mbase = mt * 64, nbase = nt * 64;
  const float* xarr[4] = {xs0, xs1, xs2, xs3};
  const float* Warr[4] = {W0, W1, W2, W3};
  const float* barr[4] = {b0, b1, b2, b3};
  constexpr int Larr[4] = {32, 16, 8, 4};
  f32x4 comb[2][2] = {};
#pragma unroll
  for (int e = 0; e < 4; ++e) {
    const int L = Larr[e];
    const float* xlast = xarr[e] + (size_t)(L - 1) * 1024;
    const size_t xstride = (size_t)L * 1024;
    const float* Wp = Warr[e];
    f32x4 acc[2][2] = {};
    for (int kt = 0; kt < 16; ++kt) {
      const int k0 = kt * 64;
      __syncthreads();
      {
        const int k_l = (tid & 15) * 4;
        const int r0 = tid >> 4;
#pragma unroll
        for (int j = 0; j < 4; ++j) {
          const int row = r0 + j * 16;
          f32x4 v = *(const f32x4*)(xlast + (size_t)(mbase + row) * xstride + (k0 + k_l));
          u16x4 pk;
          pk[0] = f2bf(v[0]); pk[1] = f2bf(v[1]); pk[2] = f2bf(v[2]); pk[3] = f2bf(v[3]);
          const int byte = (row * 128 + k_l * 2) ^ ((row & 7) << 4);
          *(u16x4*)((char*)a_lds + byte) = pk;
        }
      }
      {
        const int n_l = tid & 63;
        const int kq = tid >> 6;
        const int n_g = nbase + n_l;
        const bool nok = (n_g < 720);
        const float* wcol = Wp + n_g;
#pragma unroll
        for (int g = 0; g < 4; ++g) {
          const int k_l = kq * 4 + g * 16;
          float w0 = 0.f, w1 = 0.f, w2 = 0.f, w3 = 0.f;
          if (nok) {
            const float* s = wcol + (size_t)(k0 + k_l) * 720;
            w0 = s[0]; w1 = s[720]; w2 = s[1440]; w3 = s[2160];
          }
          u16x4 pk;
          pk[0] = f2bf(w0); pk[1] = f2bf(w1); pk[2] = f2bf(w2); pk[3] = f2bf(w3);
          const int byte = (n_l * 128 + k_l * 2) ^ ((n_l & 7) << 4);
          *(u16x4*)((char*)b_lds + byte) = pk;
        }
      }
      __syncthreads();
#pragma unroll
      for (int ks = 0; ks < 2; ++ks) {
        const int kb2 = (ks * 32 + (lane >> 4) * 8) * 2;
        bf16x8 af[2], bfr[2];
#pragma unroll
        for (int mf = 0; mf < 2; ++mf) {
          const int r = wm * 32 + mf * 16 + (lane & 15);
          const int byte = (r * 128 + kb2) ^ ((r & 7) << 4);
          af[mf] = *(const bf16x8*)((const char*)a_lds + byte);
        }
#pragma unroll
        for (int nf = 0; nf < 2; ++nf) {
          const int r = wn * 32 + nf * 16 + (lane & 15);
          const int byte = (r * 128 + kb2) ^ ((r & 7) << 4);
          bfr[nf] = *(const bf16x8*)((const char*)b_lds + byte);
        }
#pragma unroll
        for (int mf = 0; mf < 2; ++mf)
#pragma unroll
          for (int nf = 0; nf < 2; ++nf)
            acc[mf][nf] = __builtin_amdgcn_mfma_f32_16x16x32_bf16(
                af[mf], bfr[nf], acc[mf][nf], 0, 0, 0);
      }
    }
    {
      const int b_idx = mt * 2 + wm;
      const float g = gates[b_idx * 4 + e];
#pragma unroll
      for (int nf = 0; nf < 2; ++nf) {
        const int col = nbase + wn * 32 + nf * 16 + (lane & 15);
        const float bias = (col < 720) ? barr[e][col] : 0.0f;
#pragma unroll
        for (int mf = 0; mf < 2; ++mf)
#pragma unroll
          for (int j = 0; j < 4; ++j)
            comb[mf][nf][j] += g * __expf(acc[mf][nf][j] + bias);
      }
    }
  }
  {
    float* tl = &t_lds[wid][0];
#pragma unroll
    for (int mf = 0; mf < 2; ++mf)
#pragma unroll
      for (int nf = 0; nf < 2; ++nf)
#pragma unroll
        for (int j = 0; j < 4; ++j) {
          const int row_l = mf * 16 + (lane >> 4) * 4 + j;
          const int col_l = nf * 16 + (lane & 15);
          float v = comb[mf][nf][j];
          v = (v == 0.0f) ? EPSV : v;
          tl[col_l * 36 + row_l] = __logf(v);
        }
    __syncthreads();
    const int b_idx = mt * 2 + wm;
    const int pbase = nbase + wn * 32;
#pragma unroll
    for (int it = 0; it < 4; ++it) {
      const int p_l = it * 8 + (lane >> 3);
      const int p = pbase + p_l;
      if (p < 720) {
        f32x4 v = *(const f32x4*)(tl + p_l * 36 + (lane & 7) * 4);
        *(f32x4*)(out + ((size_t)b_idx * 720 + p) * 32 + (lane & 7) * 4) = v;
      }
    }
  }
}

extern "C" void kernel_launch(void* const* d_in, const int* in_sizes, int n_in,
                              void* d_out, int out_size, void* d_ws, size_t ws_size,
                              hipStream_t stream) {
  const size_t xb_elems = (size_t)4 * 2048 * 1024;
  const size_t wb_elems = (size_t)4 * 720 * 1024;
  const size_t plane_elems = (size_t)4 * 2048 * 720;
  const size_t need = (xb_elems + wb_elems) * 2 + plane_elems * 4;
  if (ws_size >= need) {
    unsigned short* Xb = (unsigned short*)d_ws;
    unsigned short* Wb = Xb + xb_elems;
    float* planes = (float*)(Wb + wb_elems);
    prep_fused<<<4096 + 768, 256, 0, stream>>>(
        (const float*)d_in[0], (const float*)d_in[1],
        (const float*)d_in[2], (const float*)d_in[3],
        (const float*)d_in[5], (const float*)d_in[7],
        (const float*)d_in[9], (const float*)d_in[11],
        Xb, Wb);
    moe_gemm_e<<<1536, 256, 0, stream>>>(
        Xb, Wb, (const float*)d_in[4],
        (const float*)d_in[6], (const float*)d_in[8],
        (const float*)d_in[10], (const float*)d_in[12],
        planes);
    reduce_log<<<dim3(12, 64), 128, 0, stream>>>(planes, (float*)d_out);
  } else {
    moe_head_fallback<<<dim3(12, 32), 256, 0, stream>>>(
        (const float*)d_in[0], (const float*)d_in[1],
        (const float*)d_in[2], (const float*)d_in[3],
        (const float*)d_in[4],
        (const float*)d_in[5], (const float*)d_in[6],
        (const float*)d_in[7], (const float*)d_in[8],
        (const float*)d_in[9], (const float*)d_in[10],
        (const float*)d_in[11], (const float*)d_in[12],
        (float*)d_out);
  }
}

// Round 5
// 39.713 us; speedup vs baseline: 3.2613x; 1.1399x over previous
//
#include <hip/hip_runtime.h>
#include <hip/hip_bf16.h>

// LinearPredictionHead: 4-expert last-token linear heads + dense-gate log-sum-exp combine.
// out[b,p,c] = log( sum_e gates[b,e] * exp( dot(xs_e[b,c,-1,:], W_e[:,p]) + b_e[p] ) )
// Round 5: BM=128x64 GEMM tiles (staging 390->295 MB), bf16 planes (write+read
// halved). Same proven single-__syncthreads 2-phase K-loop, XCD-chunked swizzle.

typedef __attribute__((ext_vector_type(4))) float f32x4;
typedef __attribute__((ext_vector_type(8))) short bf16x8;
typedef __attribute__((ext_vector_type(4))) unsigned short u16x4;
typedef __attribute__((ext_vector_type(8))) unsigned short u16x8;

#define EPSV 2.2204460492503131e-16f

__device__ __forceinline__ unsigned short f2bf(float f) {
  unsigned u = __builtin_bit_cast(unsigned, f);
  u += 0x7fffu + ((u >> 16) & 1u);   // round-to-nearest-even
  return (unsigned short)(u >> 16);
}
__device__ __forceinline__ float bf2f(unsigned short h) {
  unsigned u = ((unsigned)h) << 16;
  return __builtin_bit_cast(float, u);
}

__device__ __forceinline__ void gload_lds16(const void* g, void* l) {
  __builtin_amdgcn_global_load_lds(
      (const __attribute__((address_space(1))) unsigned int*)g,
      (__attribute__((address_space(3))) unsigned int*)l, 16, 0, 0);
}

// ---------------- prep (fused): X last tokens -> bf16 [4][2048][1024]
//                               + W [1024][720] -> bf16 W^T [4][720][1024] ----
__global__ __launch_bounds__(256) void prep_fused(
    const float* __restrict__ xs0, const float* __restrict__ xs1,
    const float* __restrict__ xs2, const float* __restrict__ xs3,
    const float* __restrict__ W0, const float* __restrict__ W1,
    const float* __restrict__ W2, const float* __restrict__ W3,
    unsigned short* __restrict__ Xb, unsigned short* __restrict__ Wb)
{
  __shared__ __align__(16) unsigned short tile[64 * 72];  // W path only
  const int tid = threadIdx.x;
  if (blockIdx.x < 4096) {
    // ---- X path (validated) ----
    const int i = blockIdx.x * 256 + tid;          // 8 elems each
    const int e = i >> 18;
    const int rem = i & 262143;
    const int m = rem >> 7;
    const int kc = rem & 127;
    const float* xp = (e == 0) ? xs0 : (e == 1) ? xs1 : (e == 2) ? xs2 : xs3;
    const int L = 32 >> e;                         // 32,16,8,4
    const float* src = xp + ((size_t)m * L + (L - 1)) * 1024 + kc * 8;
    f32x4 v0 = *(const f32x4*)src;
    f32x4 v1 = *(const f32x4*)(src + 4);
    u16x8 pk;
    pk[0] = f2bf(v0[0]); pk[1] = f2bf(v0[1]); pk[2] = f2bf(v0[2]); pk[3] = f2bf(v0[3]);
    pk[4] = f2bf(v1[0]); pk[5] = f2bf(v1[1]); pk[6] = f2bf(v1[2]); pk[7] = f2bf(v1[3]);
    *(u16x8*)(Xb + ((size_t)e * 2048 + m) * 1024 + kc * 8) = pk;
  } else {
    // ---- W path (validated) ----
    const int wI = blockIdx.x - 4096;              // 0..767 = 16 k x 12 n x 4 e
    const int k0 = (wI & 15) * 64;
    const int rest = wI >> 4;
    const int nb = (rest % 12) * 64;
    const int e = rest / 12;
    const float* Wp = (e == 0) ? W0 : (e == 1) ? W1 : (e == 2) ? W2 : W3;
    const int n_c = tid & 15;
    const int r = tid >> 4;
    const int n0 = nb + n_c * 4;
#pragma unroll
    for (int j = 0; j < 4; ++j) {
      const int row = r + j * 16;
      f32x4 v = {0.f, 0.f, 0.f, 0.f};
      if (n0 < 720) v = *(const f32x4*)(Wp + (size_t)(k0 + row) * 720 + n0);
#pragma unroll
      for (int d = 0; d < 4; ++d) tile[(n_c * 4 + d) * 72 + row] = f2bf(v[d]);
    }
    __syncthreads();
    const int n_l = tid >> 2;
    const int kq = tid & 3;
    if (nb + n_l < 720) {
#pragma unroll
      for (int q = 0; q < 2; ++q) {
        const int chunk = q * 4 + kq;
        *(u16x8*)(Wb + ((size_t)e * 720 + nb + n_l) * 1024 + k0 + chunk * 8) =
            *(const u16x8*)(tile + n_l * 72 + chunk * 8);
      }
    }
  }
}

// ---------------- GEMM per expert: planes[e][m][p] = bf16(g * exp(o_e + bias)) -
// 128x64 tile, 4 waves (2 wm x 2 wn), wave-tile 64x32, BK=64, 16 K-steps,
// dbuf LDS, single-__syncthreads 2-phase. Grid 768 = 12nt*16mt*4e,
// XCD-chunked bijection (768 % 8 == 0): each XCD gets one expert's 8 mt-panels.
__global__ __launch_bounds__(256) void moe_gemm_e(
    const unsigned short* __restrict__ Xb, const unsigned short* __restrict__ Wb,
    const float* __restrict__ gates,
    const float* __restrict__ b0, const float* __restrict__ b1,
    const float* __restrict__ b2, const float* __restrict__ b3,
    unsigned short* __restrict__ planes)
{
  __shared__ __align__(16) unsigned char smem[49152];
  unsigned short* a_lds = (unsigned short*)smem;            // [2][128*64] = 32KB
  unsigned short* b_lds = (unsigned short*)(smem + 32768);  // [2][64*64]  = 16KB

  const int tid = threadIdx.x;
  const int lane = tid & 63;
  const int wid = tid >> 6;
  const int wm = wid >> 1, wn = wid & 1;

  // XCD-chunked bijection: XCD x gets contiguous ids [x*96, (x+1)*96)
  const int id = ((int)blockIdx.x & 7) * 96 + ((int)blockIdx.x >> 3);
  const int nt = id % 12;
  const int mt = (id / 12) % 16;
  const int e  = id / 192;
  const int nbase = nt * 64;

  const float* barr[4] = {b0, b1, b2, b3};
  // wave rows mt*128 + wm*64 + mf*16: batch = mt*4 + wm*2 + (mf>>1)
  float g_r[2];
#pragma unroll
  for (int h = 0; h < 2; ++h)
    g_r[h] = gates[(mt * 4 + wm * 2 + h) * 4 + e];
  float bias_r[2];
#pragma unroll
  for (int nf = 0; nf < 2; ++nf) {
    int col = nbase + wn * 32 + nf * 16 + (lane & 15);
    bias_r[nf] = barr[e][col < 720 ? col : 719];
  }

  const unsigned short* asrc = Xb + (size_t)e * 2048 * 1024 + (size_t)mt * 128 * 1024;
  const unsigned short* bsrc = Wb + (size_t)e * 720 * 1024;

  // stage: A 128x64 (1024 chunks) + B 64x64 (512 chunks), 6 loads/thread.
  // LDS dst linear; global src pre-swizzled with the read-side XOR (m173/#21).
  auto stage = [&](int k0, int buf) {
#pragma unroll
    for (int j = 0; j < 4; ++j) {
      const int C = j * 256 + tid;
      const int row = C >> 3, c = C & 7;
      gload_lds16(asrc + (size_t)row * 1024 + k0 + ((c ^ (row & 7)) * 8),
                  a_lds + buf * 8192 + C * 8);
    }
#pragma unroll
    for (int j = 0; j < 2; ++j) {
      const int C = j * 256 + tid;
      const int row = C >> 3, c = C & 7;
      int n = nbase + row; if (n > 719) n = 719;  // clamp; stores guarded later
      gload_lds16(bsrc + (size_t)n * 1024 + k0 + ((c ^ (row & 7)) * 8),
                  b_lds + buf * 4096 + C * 8);
    }
  };

  auto compute = [&](int buf, f32x4 (&acc)[4][2]) {
    const unsigned short* al = a_lds + buf * 8192;
    const unsigned short* bl = b_lds + buf * 4096;
#pragma unroll
    for (int ks = 0; ks < 2; ++ks) {
      const int kb = ks * 64 + (lane >> 4) * 16;  // byte offset within 128B row
      bf16x8 af[4], bfm[2];
#pragma unroll
      for (int mf = 0; mf < 4; ++mf) {
        const int r = wm * 64 + mf * 16 + (lane & 15);
        const int byte = (r * 128 + kb) ^ ((r & 7) << 4);
        af[mf] = *(const bf16x8*)((const char*)al + byte);
      }
#pragma unroll
      for (int nf = 0; nf < 2; ++nf) {
        const int r = wn * 32 + nf * 16 + (lane & 15);
        const int byte = (r * 128 + kb) ^ ((r & 7) << 4);
        bfm[nf] = *(const bf16x8*)((const char*)bl + byte);
      }
#pragma unroll
      for (int mf = 0; mf < 4; ++mf)
#pragma unroll
        for (int nf = 0; nf < 2; ++nf)
          acc[mf][nf] = __builtin_amdgcn_mfma_f32_16x16x32_bf16(
              af[mf], bfm[nf], acc[mf][nf], 0, 0, 0);
    }
  };

  f32x4 acc[4][2] = {};
  int cur = 0;
  stage(0, 0);
  __syncthreads();
  for (int kt = 0; kt < 16; ++kt) {
    if (kt < 15) stage((kt + 1) * 64, cur ^ 1);  // next-tile loads fly during compute
    compute(cur, acc);
    __syncthreads();                             // drain + barrier (proven structure)
    cur ^= 1;
  }

  // epilogue: planes[e][m][p] = bf16(g * exp(acc + bias))
#pragma unroll
  for (int nf = 0; nf < 2; ++nf) {
    const int p = nbase + wn * 32 + nf * 16 + (lane & 15);
    if (p < 720) {
#pragma unroll
      for (int mf = 0; mf < 4; ++mf) {
        const int m0 = mt * 128 + wm * 64 + mf * 16 + ((lane >> 4) << 2);
        const float g = g_r[mf >> 1];
        unsigned short* dst = planes + ((size_t)e * 2048 + m0) * 720 + p;
#pragma unroll
        for (int j = 0; j < 4; ++j)
          dst[j * 720] = f2bf(g * __expf(acc[mf][nf][j] + bias_r[nf]));
      }
    }
  }
}

// ---------------- reduce: sum 4 bf16 planes, log, transpose -> out[b][p][c] ---
__global__ __launch_bounds__(256) void reduce_log(
    const unsigned short* __restrict__ planes, float* __restrict__ out)
{
  __shared__ __align__(16) float t[64 * 36];
  const int nt = blockIdx.x;         // 12 p-tiles of 64
  const int b  = blockIdx.y;         // 64 batches (32 c-rows each)
  const int nbase = nt * 64;
  const int tid = threadIdx.x;

  // phase 1: 32 c-rows x 8 p-chunks (u16x8) = 256 chunks, one per thread
  {
    const int row = tid >> 3;        // c 0..31
    const int pc = tid & 7;
    int p0 = nbase + pc * 8;
    if (p0 > 712) p0 = 712;          // clamp (t entries for p>=720 never stored)
    const size_t base = ((size_t)b * 32 + row) * 720 + p0;
    float s[8] = {};
#pragma unroll
    for (int pl = 0; pl < 4; ++pl) {
      u16x8 v = *(const u16x8*)(planes + (size_t)pl * 2048 * 720 + base);
#pragma unroll
      for (int d = 0; d < 8; ++d) s[d] += bf2f(v[d]);
    }
    const int pbase_l = (p0 - nbase);
#pragma unroll
    for (int d = 0; d < 8; ++d) {
      float v = s[d];
      v = (v == 0.0f) ? EPSV : v;
      t[(pbase_l + d) * 36 + row] = __logf(v);
    }
  }
  __syncthreads();
  // phase 2: 64 p x 8 c-chunks = 512 f32x4, two per thread
#pragma unroll
  for (int it = 0; it < 2; ++it) {
    const int i = it * 256 + tid;
    const int p_l = i >> 3;
    const int cc = i & 7;
    const int p = nbase + p_l;
    if (p < 720) {
      f32x4 v = *(const f32x4*)(t + p_l * 36 + cc * 4);
      *(f32x4*)(out + ((size_t)b * 720 + p) * 32 + cc * 4) = v;
    }
  }
}

// ---------------- round-1 fallback (used only if ws is too small) ----------------
__global__ __launch_bounds__(256) void moe_head_fallback(
    const float* __restrict__ xs0, const float* __restrict__ xs1,
    const float* __restrict__ xs2, const float* __restrict__ xs3,
    const float* __restrict__ gates,
    const float* __restrict__ W0, const float* __restrict__ b0,
    const float* __restrict__ W1, const float* __restrict__ b1,
    const float* __restrict__ W2, const float* __restrict__ b2,
    const float* __restrict__ W3, const float* __restrict__ b3,
    float* __restrict__ out)
{
  __shared__ __align__(16) unsigned short a_lds[64 * 64];
  __shared__ __align__(16) unsigned short b_lds[64 * 64];
  __shared__ __align__(16) float t_lds[4][32 * 36];
  const int tid = threadIdx.x;
  const int lane = tid & 63;
  const int wid = tid >> 6;
  const int wm = wid >> 1, wn = wid & 1;
  const int nt = blockIdx.x, mt = blockIdx.y;
  const int mbase = mt * 64, nbase = nt * 64;
  const float* xarr[4] = {xs0, xs1, xs2, xs3};
  const float* Warr[4] = {W0, W1, W2, W3};
  const float* barr[4] = {b0, b1, b2, b3};
  constexpr int Larr[4] = {32, 16, 8, 4};
  f32x4 comb[2][2] = {};
#pragma unroll
  for (int e = 0; e < 4; ++e) {
    const int L = Larr[e];
    const float* xlast = xarr[e] + (size_t)(L - 1) * 1024;
    const size_t xstride = (size_t)L * 1024;
    const float* Wp = Warr[e];
    f32x4 acc[2][2] = {};
    for (int kt = 0; kt < 16; ++kt) {
      const int k0 = kt * 64;
      __syncthreads();
      {
        const int k_l = (tid & 15) * 4;
        const int r0 = tid >> 4;
#pragma unroll
        for (int j = 0; j < 4; ++j) {
          const int row = r0 + j * 16;
          f32x4 v = *(const f32x4*)(xlast + (size_t)(mbase + row) * xstride + (k0 + k_l));
          u16x4 pk;
          pk[0] = f2bf(v[0]); pk[1] = f2bf(v[1]); pk[2] = f2bf(v[2]); pk[3] = f2bf(v[3]);
          const int byte = (row * 128 + k_l * 2) ^ ((row & 7) << 4);
          *(u16x4*)((char*)a_lds + byte) = pk;
        }
      }
      {
        const int n_l = tid & 63;
        const int kq = tid >> 6;
        const int n_g = nbase + n_l;
        const bool nok = (n_g < 720);
        const float* wcol = Wp + n_g;
#pragma unroll
        for (int g = 0; g < 4; ++g) {
          const int k_l = kq * 4 + g * 16;
          float w0 = 0.f, w1 = 0.f, w2 = 0.f, w3 = 0.f;
          if (nok) {
            const float* s = wcol + (size_t)(k0 + k_l) * 720;
            w0 = s[0]; w1 = s[720]; w2 = s[1440]; w3 = s[2160];
          }
          u16x4 pk;
          pk[0] = f2bf(w0); pk[1] = f2bf(w1); pk[2] = f2bf(w2); pk[3] = f2bf(w3);
          const int byte = (n_l * 128 + k_l * 2) ^ ((n_l & 7) << 4);
          *(u16x4*)((char*)b_lds + byte) = pk;
        }
      }
      __syncthreads();
#pragma unroll
      for (int ks = 0; ks < 2; ++ks) {
        const int kb2 = (ks * 32 + (lane >> 4) * 8) * 2;
        bf16x8 af[2], bfr[2];
#pragma unroll
        for (int mf = 0; mf < 2; ++mf) {
          const int r = wm * 32 + mf * 16 + (lane & 15);
          const int byte = (r * 128 + kb2) ^ ((r & 7) << 4);
          af[mf] = *(const bf16x8*)((const char*)a_lds + byte);
        }
#pragma unroll
        for (int nf = 0; nf < 2; ++nf) {
          const int r = wn * 32 + nf * 16 + (lane & 15);
          const int byte = (r * 128 + kb2) ^ ((r & 7) << 4);
          bfr[nf] = *(const bf16x8*)((const char*)b_lds + byte);
        }
#pragma unroll
        for (int mf = 0; mf < 2; ++mf)
#pragma unroll
          for (int nf = 0; nf < 2; ++nf)
            acc[mf][nf] = __builtin_amdgcn_mfma_f32_16x16x32_bf16(
                af[mf], bfr[nf], acc[mf][nf], 0, 0, 0);
      }
    }
    {
      const int b_idx = mt * 2 + wm;
      const float g = gates[b_idx * 4 + e];
#pragma unroll
      for (int nf = 0; nf < 2; ++nf) {
        const int col = nbase + wn * 32 + nf * 16 + (lane & 15);
        const float bias = (col < 720) ? barr[e][col] : 0.0f;
#pragma unroll
        for (int mf = 0; mf < 2; ++mf)
#pragma unroll
          for (int j = 0; j < 4; ++j)
            comb[mf][nf][j] += g * __expf(acc[mf][nf][j] + bias);
      }
    }
  }
  {
    float* tl = &t_lds[wid][0];
#pragma unroll
    for (int mf = 0; mf < 2; ++mf)
#pragma unroll
      for (int nf = 0; nf < 2; ++nf)
#pragma unroll
        for (int j = 0; j < 4; ++j) {
          const int row_l = mf * 16 + (lane >> 4) * 4 + j;
          const int col_l = nf * 16 + (lane & 15);
          float v = comb[mf][nf][j];
          v = (v == 0.0f) ? EPSV : v;
          tl[col_l * 36 + row_l] = __logf(v);
        }
    __syncthreads();
    const int b_idx = mt * 2 + wm;
    const int pbase = nbase + wn * 32;
#pragma unroll
    for (int it = 0; it < 4; ++it) {
      const int p_l = it * 8 + (lane >> 3);
      const int p = pbase + p_l;
      if (p < 720) {
        f32x4 v = *(const f32x4*)(tl + p_l * 36 + (lane & 7) * 4);
        *(f32x4*)(out + ((size_t)b_idx * 720 + p) * 32 + (lane & 7) * 4) = v;
      }
    }
  }
}

extern "C" void kernel_launch(void* const* d_in, const int* in_sizes, int n_in,
                              void* d_out, int out_size, void* d_ws, size_t ws_size,
                              hipStream_t stream) {
  const size_t xb_elems = (size_t)4 * 2048 * 1024;
  const size_t wb_elems = (size_t)4 * 720 * 1024;
  const size_t plane_elems = (size_t)4 * 2048 * 720;
  const size_t need = (xb_elems + wb_elems + plane_elems) * 2;
  if (ws_size >= need) {
    unsigned short* Xb = (unsigned short*)d_ws;
    unsigned short* Wb = Xb + xb_elems;
    unsigned short* planes = Wb + wb_elems;
    prep_fused<<<4096 + 768, 256, 0, stream>>>(
        (const float*)d_in[0], (const float*)d_in[1],
        (const float*)d_in[2], (const float*)d_in[3],
        (const float*)d_in[5], (const float*)d_in[7],
        (const float*)d_in[9], (const float*)d_in[11],
        Xb, Wb);
    moe_gemm_e<<<768, 256, 0, stream>>>(
        Xb, Wb, (const float*)d_in[4],
        (const float*)d_in[6], (const float*)d_in[8],
        (const float*)d_in[10], (const float*)d_in[12],
        planes);
    reduce_log<<<dim3(12, 64), 256, 0, stream>>>(planes, (float*)d_out);
  } else {
    moe_head_fallback<<<dim3(12, 32), 256, 0, stream>>>(
        (const float*)d_in[0], (const float*)d_in[1],
        (const float*)d_in[2], (const float*)d_in[3],
        (const float*)d_in[4],
        (const float*)d_in[5], (const float*)d_in[6],
        (const float*)d_in[7], (const float*)d_in[8],
        (const float*)d_in[9], (const float*)d_in[10],
        (const float*)d_in[11], (const float*)d_in[12],
        (float*)d_out);
  }
}

// Round 6
// 38.659 us; speedup vs baseline: 3.3502x; 1.0273x over previous
//
#include <hip/hip_runtime.h>
#include <hip/hip_bf16.h>

// LinearPredictionHead: 4-expert last-token linear heads + dense-gate log-sum-exp combine.
// out[b,p,c] = log( sum_e gates[b,e] * exp( dot(xs_e[b,c,-1,:], W_e[:,p]) + b_e[p] ) )
// Round 6: GEMM tile 128x128, 8 waves, grid 384 (all blocks co-resident, 2/CU),
// staging 295->196 MB. Same proven single-__syncthreads 2-phase K-loop,
// same swizzle pair, bf16 planes, XCD-chunked bijection.

typedef __attribute__((ext_vector_type(4))) float f32x4;
typedef __attribute__((ext_vector_type(8))) short bf16x8;
typedef __attribute__((ext_vector_type(4))) unsigned short u16x4;
typedef __attribute__((ext_vector_type(8))) unsigned short u16x8;

#define EPSV 2.2204460492503131e-16f

__device__ __forceinline__ unsigned short f2bf(float f) {
  unsigned u = __builtin_bit_cast(unsigned, f);
  u += 0x7fffu + ((u >> 16) & 1u);   // round-to-nearest-even
  return (unsigned short)(u >> 16);
}
__device__ __forceinline__ float bf2f(unsigned short h) {
  unsigned u = ((unsigned)h) << 16;
  return __builtin_bit_cast(float, u);
}

__device__ __forceinline__ void gload_lds16(const void* g, void* l) {
  __builtin_amdgcn_global_load_lds(
      (const __attribute__((address_space(1))) unsigned int*)g,
      (__attribute__((address_space(3))) unsigned int*)l, 16, 0, 0);
}

// ---------------- prep (fused): X last tokens -> bf16 [4][2048][1024]
//                               + W [1024][720] -> bf16 W^T [4][720][1024] ----
__global__ __launch_bounds__(256) void prep_fused(
    const float* __restrict__ xs0, const float* __restrict__ xs1,
    const float* __restrict__ xs2, const float* __restrict__ xs3,
    const float* __restrict__ W0, const float* __restrict__ W1,
    const float* __restrict__ W2, const float* __restrict__ W3,
    unsigned short* __restrict__ Xb, unsigned short* __restrict__ Wb)
{
  __shared__ __align__(16) unsigned short tile[64 * 72];  // W path only
  const int tid = threadIdx.x;
  if (blockIdx.x < 4096) {
    // ---- X path (validated) ----
    const int i = blockIdx.x * 256 + tid;          // 8 elems each
    const int e = i >> 18;
    const int rem = i & 262143;
    const int m = rem >> 7;
    const int kc = rem & 127;
    const float* xp = (e == 0) ? xs0 : (e == 1) ? xs1 : (e == 2) ? xs2 : xs3;
    const int L = 32 >> e;                         // 32,16,8,4
    const float* src = xp + ((size_t)m * L + (L - 1)) * 1024 + kc * 8;
    f32x4 v0 = *(const f32x4*)src;
    f32x4 v1 = *(const f32x4*)(src + 4);
    u16x8 pk;
    pk[0] = f2bf(v0[0]); pk[1] = f2bf(v0[1]); pk[2] = f2bf(v0[2]); pk[3] = f2bf(v0[3]);
    pk[4] = f2bf(v1[0]); pk[5] = f2bf(v1[1]); pk[6] = f2bf(v1[2]); pk[7] = f2bf(v1[3]);
    *(u16x8*)(Xb + ((size_t)e * 2048 + m) * 1024 + kc * 8) = pk;
  } else {
    // ---- W path (validated) ----
    const int wI = blockIdx.x - 4096;              // 0..767 = 16 k x 12 n x 4 e
    const int k0 = (wI & 15) * 64;
    const int rest = wI >> 4;
    const int nb = (rest % 12) * 64;
    const int e = rest / 12;
    const float* Wp = (e == 0) ? W0 : (e == 1) ? W1 : (e == 2) ? W2 : W3;
    const int n_c = tid & 15;
    const int r = tid >> 4;
    const int n0 = nb + n_c * 4;
#pragma unroll
    for (int j = 0; j < 4; ++j) {
      const int row = r + j * 16;
      f32x4 v = {0.f, 0.f, 0.f, 0.f};
      if (n0 < 720) v = *(const f32x4*)(Wp + (size_t)(k0 + row) * 720 + n0);
#pragma unroll
      for (int d = 0; d < 4; ++d) tile[(n_c * 4 + d) * 72 + row] = f2bf(v[d]);
    }
    __syncthreads();
    const int n_l = tid >> 2;
    const int kq = tid & 3;
    if (nb + n_l < 720) {
#pragma unroll
      for (int q = 0; q < 2; ++q) {
        const int chunk = q * 4 + kq;
        *(u16x8*)(Wb + ((size_t)e * 720 + nb + n_l) * 1024 + k0 + chunk * 8) =
            *(const u16x8*)(tile + n_l * 72 + chunk * 8);
      }
    }
  }
}

// ---------------- GEMM per expert: planes[e][m][p] = bf16(g * exp(o_e + bias)) -
// 128x128 tile, 8 waves (2 wm x 4 wn), wave-tile 64x32, BK=64, 16 K-steps,
// dbuf LDS (64KB), single-__syncthreads 2-phase. Grid 384 = 6nt*16mt*4e,
// XCD-chunked bijection (384 % 8 == 0): each XCD = one expert's 8 mt-panels.
__global__ __launch_bounds__(512) void moe_gemm_e(
    const unsigned short* __restrict__ Xb, const unsigned short* __restrict__ Wb,
    const float* __restrict__ gates,
    const float* __restrict__ b0, const float* __restrict__ b1,
    const float* __restrict__ b2, const float* __restrict__ b3,
    unsigned short* __restrict__ planes)
{
  __shared__ __align__(16) unsigned char smem[65536];
  unsigned short* a_lds = (unsigned short*)smem;            // [2][128*64] = 32KB
  unsigned short* b_lds = (unsigned short*)(smem + 32768);  // [2][128*64] = 32KB

  const int tid = threadIdx.x;
  const int lane = tid & 63;
  const int wid = tid >> 6;          // 0..7
  const int wm = wid >> 2;           // 0..1 : 64-row half
  const int wn = wid & 3;            // 0..3 : 32-col quarter

  // XCD-chunked bijection: XCD x gets contiguous ids [x*48, (x+1)*48)
  const int id = ((int)blockIdx.x & 7) * 48 + ((int)blockIdx.x >> 3);
  const int nt = id % 6;             // 6 N-tiles of 128 (last ragged: 720-640=80)
  const int mt = (id / 6) % 16;      // 16 M-tiles of 128
  const int e  = id / 96;
  const int nbase = nt * 128;

  const float* barr[4] = {b0, b1, b2, b3};
  // wave rows mt*128 + wm*64 + mf*16: batch = mt*4 + wm*2 + (mf>>1)
  float g_r[2];
#pragma unroll
  for (int h = 0; h < 2; ++h)
    g_r[h] = gates[(mt * 4 + wm * 2 + h) * 4 + e];
  float bias_r[2];
#pragma unroll
  for (int nf = 0; nf < 2; ++nf) {
    int col = nbase + wn * 32 + nf * 16 + (lane & 15);
    bias_r[nf] = barr[e][col < 720 ? col : 719];
  }

  const unsigned short* asrc = Xb + (size_t)e * 2048 * 1024 + (size_t)mt * 128 * 1024;
  const unsigned short* bsrc = Wb + (size_t)e * 720 * 1024;

  // stage: A 128x64 (1024 chunks) + B 128x64 (1024 chunks), 4 loads/thread.
  // LDS dst linear; global src pre-swizzled with the read-side XOR (m173/#21).
  auto stage = [&](int k0, int buf) {
#pragma unroll
    for (int j = 0; j < 2; ++j) {
      const int C = j * 512 + tid;
      const int row = C >> 3, c = C & 7;
      gload_lds16(asrc + (size_t)row * 1024 + k0 + ((c ^ (row & 7)) * 8),
                  a_lds + buf * 8192 + C * 8);
    }
#pragma unroll
    for (int j = 0; j < 2; ++j) {
      const int C = j * 512 + tid;
      const int row = C >> 3, c = C & 7;
      int n = nbase + row; if (n > 719) n = 719;  // clamp; stores guarded later
      gload_lds16(bsrc + (size_t)n * 1024 + k0 + ((c ^ (row & 7)) * 8),
                  b_lds + buf * 8192 + C * 8);
    }
  };

  auto compute = [&](int buf, f32x4 (&acc)[4][2]) {
    const unsigned short* al = a_lds + buf * 8192;
    const unsigned short* bl = b_lds + buf * 8192;
#pragma unroll
    for (int ks = 0; ks < 2; ++ks) {
      const int kb = ks * 64 + (lane >> 4) * 16;  // byte offset within 128B row
      bf16x8 af[4], bfm[2];
#pragma unroll
      for (int mf = 0; mf < 4; ++mf) {
        const int r = wm * 64 + mf * 16 + (lane & 15);
        const int byte = (r * 128 + kb) ^ ((r & 7) << 4);
        af[mf] = *(const bf16x8*)((const char*)al + byte);
      }
#pragma unroll
      for (int nf = 0; nf < 2; ++nf) {
        const int r = wn * 32 + nf * 16 + (lane & 15);
        const int byte = (r * 128 + kb) ^ ((r & 7) << 4);
        bfm[nf] = *(const bf16x8*)((const char*)bl + byte);
      }
#pragma unroll
      for (int mf = 0; mf < 4; ++mf)
#pragma unroll
        for (int nf = 0; nf < 2; ++nf)
          acc[mf][nf] = __builtin_amdgcn_mfma_f32_16x16x32_bf16(
              af[mf], bfm[nf], acc[mf][nf], 0, 0, 0);
    }
  };

  f32x4 acc[4][2] = {};
  int cur = 0;
  stage(0, 0);
  __syncthreads();
  for (int kt = 0; kt < 16; ++kt) {
    if (kt < 15) stage((kt + 1) * 64, cur ^ 1);  // next-tile loads fly during compute
    compute(cur, acc);
    __syncthreads();                             // drain + barrier (proven structure)
    cur ^= 1;
  }

  // epilogue: planes[e][m][p] = bf16(g * exp(acc + bias))
#pragma unroll
  for (int nf = 0; nf < 2; ++nf) {
    const int p = nbase + wn * 32 + nf * 16 + (lane & 15);
    if (p < 720) {
#pragma unroll
      for (int mf = 0; mf < 4; ++mf) {
        const int m0 = mt * 128 + wm * 64 + mf * 16 + ((lane >> 4) << 2);
        const float g = g_r[mf >> 1];
        unsigned short* dst = planes + ((size_t)e * 2048 + m0) * 720 + p;
#pragma unroll
        for (int j = 0; j < 4; ++j)
          dst[j * 720] = f2bf(g * __expf(acc[mf][nf][j] + bias_r[nf]));
      }
    }
  }
}

// ---------------- reduce: sum 4 bf16 planes, log, transpose -> out[b][p][c] ---
__global__ __launch_bounds__(256) void reduce_log(
    const unsigned short* __restrict__ planes, float* __restrict__ out)
{
  __shared__ __align__(16) float t[64 * 36];
  const int nt = blockIdx.x;         // 12 p-tiles of 64
  const int b  = blockIdx.y;         // 64 batches (32 c-rows each)
  const int nbase = nt * 64;
  const int tid = threadIdx.x;

  // phase 1: 32 c-rows x 8 p-chunks (u16x8) = 256 chunks, one per thread
  {
    const int row = tid >> 3;        // c 0..31
    const int pc = tid & 7;
    int p0 = nbase + pc * 8;
    if (p0 > 712) p0 = 712;          // clamp (t entries for p>=720 never stored)
    const size_t base = ((size_t)b * 32 + row) * 720 + p0;
    float s[8] = {};
#pragma unroll
    for (int pl = 0; pl < 4; ++pl) {
      u16x8 v = *(const u16x8*)(planes + (size_t)pl * 2048 * 720 + base);
#pragma unroll
      for (int d = 0; d < 8; ++d) s[d] += bf2f(v[d]);
    }
    const int pbase_l = (p0 - nbase);
#pragma unroll
    for (int d = 0; d < 8; ++d) {
      float v = s[d];
      v = (v == 0.0f) ? EPSV : v;
      t[(pbase_l + d) * 36 + row] = __logf(v);
    }
  }
  __syncthreads();
  // phase 2: 64 p x 8 c-chunks = 512 f32x4, two per thread
#pragma unroll
  for (int it = 0; it < 2; ++it) {
    const int i = it * 256 + tid;
    const int p_l = i >> 3;
    const int cc = i & 7;
    const int p = nbase + p_l;
    if (p < 720) {
      f32x4 v = *(const f32x4*)(t + p_l * 36 + cc * 4);
      *(f32x4*)(out + ((size_t)b * 720 + p) * 32 + cc * 4) = v;
    }
  }
}

// ---------------- round-1 fallback (used only if ws is too small) ----------------
__global__ __launch_bounds__(256) void moe_head_fallback(
    const float* __restrict__ xs0, const float* __restrict__ xs1,
    const float* __restrict__ xs2, const float* __restrict__ xs3,
    const float* __restrict__ gates,
    const float* __restrict__ W0, const float* __restrict__ b0,
    const float* __restrict__ W1, const float* __restrict__ b1,
    const float* __restrict__ W2, const float* __restrict__ b2,
    const float* __restrict__ W3, const float* __restrict__ b3,
    float* __restrict__ out)
{
  __shared__ __align__(16) unsigned short a_lds[64 * 64];
  __shared__ __align__(16) unsigned short b_lds[64 * 64];
  __shared__ __align__(16) float t_lds[4][32 * 36];
  const int tid = threadIdx.x;
  const int lane = tid & 63;
  const int wid = tid >> 6;
  const int wm = wid >> 1, wn = wid & 1;
  const int nt = blockIdx.x, mt = blockIdx.y;
  const int mbase = mt * 64, nbase = nt * 64;
  const float* xarr[4] = {xs0, xs1, xs2, xs3};
  const float* Warr[4] = {W0, W1, W2, W3};
  const float* barr[4] = {b0, b1, b2, b3};
  constexpr int Larr[4] = {32, 16, 8, 4};
  f32x4 comb[2][2] = {};
#pragma unroll
  for (int e = 0; e < 4; ++e) {
    const int L = Larr[e];
    const float* xlast = xarr[e] + (size_t)(L - 1) * 1024;
    const size_t xstride = (size_t)L * 1024;
    const float* Wp = Warr[e];
    f32x4 acc[2][2] = {};
    for (int kt = 0; kt < 16; ++kt) {
      const int k0 = kt * 64;
      __syncthreads();
      {
        const int k_l = (tid & 15) * 4;
        const int r0 = tid >> 4;
#pragma unroll
        for (int j = 0; j < 4; ++j) {
          const int row = r0 + j * 16;
          f32x4 v = *(const f32x4*)(xlast + (size_t)(mbase + row) * xstride + (k0 + k_l));
          u16x4 pk;
          pk[0] = f2bf(v[0]); pk[1] = f2bf(v[1]); pk[2] = f2bf(v[2]); pk[3] = f2bf(v[3]);
          const int byte = (row * 128 + k_l * 2) ^ ((row & 7) << 4);
          *(u16x4*)((char*)a_lds + byte) = pk;
        }
      }
      {
        const int n_l = tid & 63;
        const int kq = tid >> 6;
        const int n_g = nbase + n_l;
        const bool nok = (n_g < 720);
        const float* wcol = Wp + n_g;
#pragma unroll
        for (int g = 0; g < 4; ++g) {
          const int k_l = kq * 4 + g * 16;
          float w0 = 0.f, w1 = 0.f, w2 = 0.f, w3 = 0.f;
          if (nok) {
            const float* s = wcol + (size_t)(k0 + k_l) * 720;
            w0 = s[0]; w1 = s[720]; w2 = s[1440]; w3 = s[2160];
          }
          u16x4 pk;
          pk[0] = f2bf(w0); pk[1] = f2bf(w1); pk[2] = f2bf(w2); pk[3] = f2bf(w3);
          const int byte = (n_l * 128 + k_l * 2) ^ ((n_l & 7) << 4);
          *(u16x4*)((char*)b_lds + byte) = pk;
        }
      }
      __syncthreads();
#pragma unroll
      for (int ks = 0; ks < 2; ++ks) {
        const int kb2 = (ks * 32 + (lane >> 4) * 8) * 2;
        bf16x8 af[2], bfr[2];
#pragma unroll
        for (int mf = 0; mf < 2; ++mf) {
          const int r = wm * 32 + mf * 16 + (lane & 15);
          const int byte = (r * 128 + kb2) ^ ((r & 7) << 4);
          af[mf] = *(const bf16x8*)((const char*)a_lds + byte);
        }
#pragma unroll
        for (int nf = 0; nf < 2; ++nf) {
          const int r = wn * 32 + nf * 16 + (lane & 15);
          const int byte = (r * 128 + kb2) ^ ((r & 7) << 4);
          bfr[nf] = *(const bf16x8*)((const char*)b_lds + byte);
        }
#pragma unroll
        for (int mf = 0; mf < 2; ++mf)
#pragma unroll
          for (int nf = 0; nf < 2; ++nf)
            acc[mf][nf] = __builtin_amdgcn_mfma_f32_16x16x32_bf16(
                af[mf], bfr[nf], acc[mf][nf], 0, 0, 0);
      }
    }
    {
      const int b_idx = mt * 2 + wm;
      const float g = gates[b_idx * 4 + e];
#pragma unroll
      for (int nf = 0; nf < 2; ++nf) {
        const int col = nbase + wn * 32 + nf * 16 + (lane & 15);
        const float bias = (col < 720) ? barr[e][col] : 0.0f;
#pragma unroll
        for (int mf = 0; mf < 2; ++mf)
#pragma unroll
          for (int j = 0; j < 4; ++j)
            comb[mf][nf][j] += g * __expf(acc[mf][nf][j] + bias);
      }
    }
  }
  {
    float* tl = &t_lds[wid][0];
#pragma unroll
    for (int mf = 0; mf < 2; ++mf)
#pragma unroll
      for (int nf = 0; nf < 2; ++nf)
#pragma unroll
        for (int j = 0; j < 4; ++j) {
          const int row_l = mf * 16 + (lane >> 4) * 4 + j;
          const int col_l = nf * 16 + (lane & 15);
          float v = comb[mf][nf][j];
          v = (v == 0.0f) ? EPSV : v;
          tl[col_l * 36 + row_l] = __logf(v);
        }
    __syncthreads();
    const int b_idx = mt * 2 + wm;
    const int pbase = nbase + wn * 32;
#pragma unroll
    for (int it = 0; it < 4; ++it) {
      const int p_l = it * 8 + (lane >> 3);
      const int p = pbase + p_l;
      if (p < 720) {
        f32x4 v = *(const f32x4*)(tl + p_l * 36 + (lane & 7) * 4);
        *(f32x4*)(out + ((size_t)b_idx * 720 + p) * 32 + (lane & 7) * 4) = v;
      }
    }
  }
}

extern "C" void kernel_launch(void* const* d_in, const int* in_sizes, int n_in,
                              void* d_out, int out_size, void* d_ws, size_t ws_size,
                              hipStream_t stream) {
  const size_t xb_elems = (size_t)4 * 2048 * 1024;
  const size_t wb_elems = (size_t)4 * 720 * 1024;
  const size_t plane_elems = (size_t)4 * 2048 * 720;
  const size_t need = (xb_elems + wb_elems + plane_elems) * 2;
  if (ws_size >= need) {
    unsigned short* Xb = (unsigned short*)d_ws;
    unsigned short* Wb = Xb + xb_elems;
    unsigned short* planes = Wb + wb_elems;
    prep_fused<<<4096 + 768, 256, 0, stream>>>(
        (const float*)d_in[0], (const float*)d_in[1],
        (const float*)d_in[2], (const float*)d_in[3],
        (const float*)d_in[5], (const float*)d_in[7],
        (const float*)d_in[9], (const float*)d_in[11],
        Xb, Wb);
    moe_gemm_e<<<384, 512, 0, stream>>>(
        Xb, Wb, (const float*)d_in[4],
        (const float*)d_in[6], (const float*)d_in[8],
        (const float*)d_in[10], (const float*)d_in[12],
        planes);
    reduce_log<<<dim3(12, 64), 256, 0, stream>>>(planes, (float*)d_out);
  } else {
    moe_head_fallback<<<dim3(12, 32), 256, 0, stream>>>(
        (const float*)d_in[0], (const float*)d_in[1],
        (const float*)d_in[2], (const float*)d_in[3],
        (const float*)d_in[4],
        (const float*)d_in[5], (const float*)d_in[6],
        (const float*)d_in[7], (const float*)d_in[8],
        (const float*)d_in[9], (const float*)d_in[10],
        (const float*)d_in[11], (const float*)d_in[12],
        (float*)d_out);
  }
}